// Round 4
// baseline (1094.299 us; speedup 1.0000x reference)
//
#include <hip/hip_runtime.h>

#define N_NODES 50000
#define N_EDGES 800000
#define F 64
#define EDIM 16
#define NPB 50            // dst nodes per block (NPB * NBLK == N_NODES)
#define NBLK 1000
#define TPB 512           // 8 waves
#define NWAVE 8
#define NEG_SLOPE 0.01f

// ---------------- CSR build ----------------
__global__ __launch_bounds__(256) void hist_kernel(const int* __restrict__ ei,
                                                   int* __restrict__ count) {
    for (int e = blockIdx.x * blockDim.x + threadIdx.x; e < N_EDGES;
         e += gridDim.x * blockDim.x)
        atomicAdd(&count[ei[N_EDGES + e]], 1);
}

__global__ __launch_bounds__(1024) void scan_kernel(const int* __restrict__ count,
                                                    int* __restrict__ rowptr,
                                                    int* __restrict__ cursor) {
    __shared__ int buf[1024];
    const int tid = threadIdx.x;
    int run = 0;
    for (int base = 0; base < N_NODES; base += 1024) {
        int i = base + tid;
        int v = (i < N_NODES) ? count[i] : 0;
        buf[tid] = v;
        __syncthreads();
        for (int off = 1; off < 1024; off <<= 1) {
            int t = (tid >= off) ? buf[tid - off] : 0;
            __syncthreads();
            buf[tid] += t;
            __syncthreads();
        }
        int excl = buf[tid] - v;
        if (i < N_NODES) { rowptr[i] = run + excl; cursor[i] = run + excl; }
        run += buf[1023];
        __syncthreads();
    }
    if (tid == 0) rowptr[N_NODES] = run;
}

// pairsSD[pos] = (src, dst); eid[pos] = original edge id
__global__ __launch_bounds__(256) void scatter_kernel(const int* __restrict__ ei,
                                                      int* __restrict__ cursor,
                                                      int2* __restrict__ pairsSD,
                                                      int* __restrict__ eid) {
    for (int e = blockIdx.x * blockDim.x + threadIdx.x; e < N_EDGES;
         e += gridDim.x * blockDim.x) {
        int s = ei[e];
        int d = ei[N_EDGES + e];
        int pos = atomicAdd(&cursor[d], 1);
        pairsSD[pos] = make_int2(s, d);
        eid[pos] = e;
    }
}

// eaP[j][:] = ea[eid[j]][:]  (one float4 per thread)
__global__ __launch_bounds__(256) void permute_kernel(const float4* __restrict__ ea4,
                                                      const int* __restrict__ eid,
                                                      float4* __restrict__ eaP) {
    int t = blockIdx.x * blockDim.x + threadIdx.x;
    if (t < N_EDGES * 4) {
        int j = t >> 2, c = t & 3;
        eaP[t] = ea4[((size_t)eid[j] << 2) + c];
    }
}

// ---------------- fuse readout weights ----------------
__global__ void fuse_weights_kernel(
    const float* __restrict__ W1, const float* __restrict__ b1,
    const float* __restrict__ W2, const float* __restrict__ b2,
    float* __restrict__ Wf, float* __restrict__ bf) {
    const int t = threadIdx.x;     // 128 threads
    const int i = t >> 1;
    const int j = t & 1;
    float acc = 0.f;
    for (int k = 0; k < 128; ++k) acc += W1[i * 128 + k] * W2[k * 2 + j];
    Wf[i * 2 + j] = acc;
    if (i == 0) {
        float accb = b2[j];
        for (int k = 0; k < 128; ++k) accb += b1[k] * W2[k * 2 + j];
        bf[j] = accb;
    }
}

// ---------------- fused GINE layer: LDS dst-tile aggregation + node GEMM ----------------
template <bool LAST>
__global__ __launch_bounds__(TPB) void conv_kernel(
    const float* __restrict__ h,
    const int* __restrict__ rowptr,
    const int2* __restrict__ pairsSD,
    const int* __restrict__ eid,
    const float* __restrict__ eaSrc,   // eaP (CSR order) or ea (orig order)
    const int usePerm,
    const float* __restrict__ We, const float* __restrict__ be,
    const float* __restrict__ Wn, const float* __restrict__ bn,
    const float* __restrict__ Wf, const float* __restrict__ bf,
    float* __restrict__ hout, float* __restrict__ out) {
    __shared__ float aggrS[NPB * F];   // 12.8 KB
    const int tid  = threadIdx.x;
    const int lane = tid & 63;
    const int wid  = tid >> 6;
    const int n0   = blockIdx.x * NPB;

    for (int i = tid; i < NPB * F; i += TPB) aggrS[i] = 0.f;

    // We column for this lane lives in registers (no LDS in the edge loop)
    float weR[EDIM];
#pragma unroll
    for (int k = 0; k < EDIM; ++k) weR[k] = We[k * F + lane];
    const float beR = be[lane];

    __syncthreads();

    const int eBeg = rowptr[n0];
    const int eEnd = rowptr[n0 + NPB];

    // independent edge iterations; ds_add into the LDS tile (lane=feature: conflict-free)
    for (int j = eBeg + wid; j < eEnd; j += NWAVE) {
        int2 sd = pairsSD[j];
        const float4* ep = (const float4*)eaSrc +
                           ((usePerm ? (size_t)j : (size_t)eid[j]) << 2);
        float4 e0 = ep[0], e1 = ep[1], e2 = ep[2], e3 = ep[3];
        float hs = h[((size_t)sd.x << 6) + lane];
        float acc = beR;
        acc = fmaf(e0.x, weR[0],  acc); acc = fmaf(e0.y, weR[1],  acc);
        acc = fmaf(e0.z, weR[2],  acc); acc = fmaf(e0.w, weR[3],  acc);
        acc = fmaf(e1.x, weR[4],  acc); acc = fmaf(e1.y, weR[5],  acc);
        acc = fmaf(e1.z, weR[6],  acc); acc = fmaf(e1.w, weR[7],  acc);
        acc = fmaf(e2.x, weR[8],  acc); acc = fmaf(e2.y, weR[9],  acc);
        acc = fmaf(e2.z, weR[10], acc); acc = fmaf(e2.w, weR[11], acc);
        acc = fmaf(e3.x, weR[12], acc); acc = fmaf(e3.y, weR[13], acc);
        acc = fmaf(e3.z, weR[14], acc); acc = fmaf(e3.w, weR[15], acc);
        float m = hs + acc;
        m = fmaxf(m, 0.f);                               // ReLU
        atomicAdd(&aggrS[((sd.y - n0) << 6) + lane], m); // ds_add_f32
    }
    __syncthreads();

    // t = h + aggr, written back in place
    for (int nl = wid; nl < NPB; nl += NWAVE)
        aggrS[(nl << 6) + lane] += h[((size_t)(n0 + nl) << 6) + lane];
    __syncthreads();

    // node GEMM: Wn column in registers, t via uniform b128 LDS broadcasts
    float wnR[F];
#pragma unroll
    for (int k = 0; k < F; ++k) wnR[k] = Wn[k * F + lane];
    const float bnR = bn[lane];
    float wf0 = 0.f, wf1 = 0.f, bf0 = 0.f, bf1 = 0.f;
    if (LAST) { wf0 = Wf[lane * 2]; wf1 = Wf[lane * 2 + 1]; bf0 = bf[0]; bf1 = bf[1]; }

    for (int nl = wid; nl < NPB; nl += NWAVE) {
        const float4* tp = (const float4*)&aggrS[nl << 6];
        float acc = bnR;
#pragma unroll
        for (int q = 0; q < 16; ++q) {
            float4 t4 = tp[q];
            acc = fmaf(t4.x, wnR[4 * q + 0], acc);
            acc = fmaf(t4.y, wnR[4 * q + 1], acc);
            acc = fmaf(t4.z, wnR[4 * q + 2], acc);
            acc = fmaf(t4.w, wnR[4 * q + 3], acc);
        }
        acc = acc >= 0.f ? acc : NEG_SLOPE * acc;        // LeakyReLU
        if (!LAST) {
            hout[((size_t)(n0 + nl) << 6) + lane] = acc;
        } else {
            float v0 = acc * wf0, v1 = acc * wf1;
#pragma unroll
            for (int off = 32; off; off >>= 1) {
                v0 += __shfl_down(v0, off);
                v1 += __shfl_down(v1, off);
            }
            if (lane == 0) {
                out[(n0 + nl) * 2 + 0] = v0 + bf0;
                out[(n0 + nl) * 2 + 1] = v1 + bf1;
            }
        }
    }
}

extern "C" void kernel_launch(void* const* d_in, const int* in_sizes, int n_in,
                              void* d_out, int out_size, void* d_ws, size_t ws_size,
                              hipStream_t stream) {
    const float* x  = (const float*)d_in[0];
    const int*   ei = (const int*)d_in[1];
    const float* ea = (const float*)d_in[2];
    const float* Wn = (const float*)d_in[3];
    const float* bn = (const float*)d_in[4];
    const float* We = (const float*)d_in[5];     // [3,16,64]
    const float* be = (const float*)d_in[6];     // [3,64]
    const float* W1 = (const float*)d_in[7];
    const float* b1 = (const float*)d_in[8];
    const float* W2 = (const float*)d_in[9];
    const float* b2 = (const float*)d_in[10];
    float* out = (float*)d_out;

    size_t off = 0;
    char* base = (char*)d_ws;
    auto alloc = [&](size_t bytes) {
        off = (off + 15) & ~(size_t)15;
        char* p = base + off;
        off += bytes;
        return p;
    };
    int*   count   = (int*)alloc(sizeof(int) * N_NODES);
    int*   rowptr  = (int*)alloc(sizeof(int) * (N_NODES + 1));
    int*   cursor  = (int*)alloc(sizeof(int) * N_NODES);
    int2*  pairsSD = (int2*)alloc(sizeof(int2) * N_EDGES);
    int*   eid     = (int*)alloc(sizeof(int) * N_EDGES);
    float* hA      = (float*)alloc(sizeof(float) * (size_t)N_NODES * F);
    float* hB      = (float*)alloc(sizeof(float) * (size_t)N_NODES * F);
    float* Wf      = (float*)alloc(sizeof(float) * F * 2);
    float* bf      = (float*)alloc(sizeof(float) * 2);
    size_t need_base = off;
    float* eaP     = (float*)alloc(sizeof(float) * (size_t)N_EDGES * EDIM);
    const int usePerm = (ws_size >= off) ? 1 : 0;
    (void)need_base;

    fuse_weights_kernel<<<1, 128, 0, stream>>>(W1, b1, W2, b2, Wf, bf);

    // CSR build (edge_index is layer-invariant)
    hipMemsetAsync(count, 0, sizeof(int) * N_NODES, stream);
    hist_kernel<<<1024, 256, 0, stream>>>(ei, count);
    scan_kernel<<<1, 1024, 0, stream>>>(count, rowptr, cursor);
    scatter_kernel<<<1024, 256, 0, stream>>>(ei, cursor, pairsSD, eid);
    if (usePerm)
        permute_kernel<<<(N_EDGES * 4 + 255) / 256, 256, 0, stream>>>(
            (const float4*)ea, eid, (float4*)eaP);

    const float* eaSrc = usePerm ? eaP : ea;
    conv_kernel<false><<<NBLK, TPB, 0, stream>>>(x, rowptr, pairsSD, eid, eaSrc, usePerm,
        We + 0 * EDIM * F, be + 0 * F, Wn, bn, Wf, bf, hA, out);
    conv_kernel<false><<<NBLK, TPB, 0, stream>>>(hA, rowptr, pairsSD, eid, eaSrc, usePerm,
        We + 1 * EDIM * F, be + 1 * F, Wn, bn, Wf, bf, hB, out);
    conv_kernel<true><<<NBLK, TPB, 0, stream>>>(hB, rowptr, pairsSD, eid, eaSrc, usePerm,
        We + 2 * EDIM * F, be + 2 * F, Wn, bn, Wf, bf, nullptr, out);
}